// Round 9
// baseline (117.897 us; speedup 1.0000x reference)
//
#include <hip/hip_runtime.h>
#include <hip/hip_bf16.h>
#include <math.h>

#define NTOK  16384
#define INF   2048
#define OUTF  2048
#define SR    45
#define RANK  8
#define BLK   64
#define NBLK  32
#define NRULE 256
#define NHIST 32
#define MAXSLOT (NTOK + NRULE * 15)   // 20224
#define NTILE32 (MAXSLOT / 32)        // 632 tiles of 32 slots

typedef __attribute__((ext_vector_type(8))) short bf16x8;
typedef __attribute__((ext_vector_type(4))) float f32x4;
typedef __attribute__((ext_vector_type(4))) short s16x4;

#define MFMA __builtin_amdgcn_mfma_f32_16x16x32_bf16
#define SBAR() __builtin_amdgcn_sched_barrier(0)

__device__ inline short f2bs(float f) {
    __hip_bfloat16 h = __float2bfloat16(f);
    return *reinterpret_cast<short*>(&h);
}
__device__ inline bf16x8 cvt8(const float4& a, const float4& b) {
    bf16x8 r;
    r[0] = f2bs(a.x); r[1] = f2bs(a.y); r[2] = f2bs(a.z); r[3] = f2bs(a.w);
    r[4] = f2bs(b.x); r[5] = f2bs(b.y); r[6] = f2bs(b.z); r[7] = f2bs(b.w);
    return r;
}

// ---------------------------------------------------------------------------
// prep A: blocks 0..127 pack weights into MFMA B-frag layout (bf16);
//         blocks 128..159 per-block histogram slabs + init perm/srid.
// B-frag (16x16x32): lane l holds B[k=(l>>4)*8+j][col=l&15], j=0..7.
// ---------------------------------------------------------------------------
__global__ void kprep_a(const int* __restrict__ rule_ids,
                        const float* __restrict__ shared_in,
                        const float* __restrict__ shared_out,
                        const float* __restrict__ rule_in,
                        const float* __restrict__ rule_out,
                        unsigned short* __restrict__ ssb,   // [64ch][3nf][64][8]
                        unsigned short* __restrict__ sob,   // [128CF][2kc][64][8]
                        unsigned short* __restrict__ rinf,  // [256][2half][64][8]
                        unsigned short* __restrict__ rof,   // [256][4cf][64][8]
                        int* __restrict__ ghist_part,       // [32][256]
                        int* __restrict__ perm_p,
                        int* __restrict__ srid_p)
{
    if (blockIdx.x < 128) {
        const int tid = blockIdx.x * 256 + threadIdx.x;
        const int stride = 128 * 256;
        for (int idx = tid; idx < 64 * 3 * 512; idx += stride) {
            int ch = idx / 1536, rem = idx - ch * 1536;
            int nf = rem / 512;
            int l = (rem >> 3) & 63, j = idx & 7;
            int k = ch * 32 + ((l >> 4) << 3) + j;
            int col = nf * 16 + (l & 15);
            ssb[idx] = (col < SR) ? (unsigned short)f2bs(shared_in[(size_t)k * SR + col]) : 0;
        }
        for (int idx = tid; idx < 128 * 2 * 512; idx += stride) {
            int CF = idx >> 10;
            int kc = (idx >> 9) & 1;
            int l = (idx >> 3) & 63, j = idx & 7;
            int k = kc * 32 + ((l >> 4) << 3) + j;
            int col = CF * 16 + (l & 15);
            sob[idx] = (k < SR) ? (unsigned short)f2bs(shared_out[(size_t)k * OUTF + col]) : 0;
        }
        for (int idx = tid; idx < NRULE * 2 * 512; idx += stride) {
            int rid = idx >> 10;
            int half = (idx >> 9) & 1;
            int l = (idx >> 3) & 63, j = idx & 7;
            int r = l & 15;
            int s = half * 32 + ((l >> 4) << 3) + j;
            rinf[idx] = (r < RANK) ? (unsigned short)f2bs(rule_in[(size_t)rid * 512 + s * RANK + r]) : 0;
        }
        for (int idx = tid; idx < NRULE * 4 * 512; idx += stride) {
            int rid = idx >> 11;
            int cf = (idx >> 9) & 3;
            int l = (idx >> 3) & 63, j = idx & 7;
            int k = ((l >> 4) << 3) + j;
            int c = cf * 16 + (l & 15);
            rof[idx] = (k < RANK) ? (unsigned short)f2bs(rule_out[(size_t)rid * 512 + k * BLK + c]) : 0;
        }
    } else {
        __shared__ int lh[NRULE];
        const int tid = threadIdx.x;
        const int hb = blockIdx.x - 128;          // 0..31
        lh[tid] = 0;
        __syncthreads();
        const int base = hb * 512;
        atomicAdd(&lh[rule_ids[base + tid]], 1);
        atomicAdd(&lh[rule_ids[base + 256 + tid]], 1);
        __syncthreads();
        ghist_part[hb * NRULE + tid] = lh[tid];
        for (int j = tid; j < MAXSLOT / 32; j += 256) {
            int idx = hb * (MAXSLOT / 32) + j;
            perm_p[idx] = -1;
            srid_p[idx] = 0;
        }
    }
}

// ---------------------------------------------------------------------------
// prep B (1 block, 256 thr): sum hist slabs, scan, pad srid, sel, ntot
// ---------------------------------------------------------------------------
__global__ void kprep_scan(const int* __restrict__ ghist_part,
                           const float* __restrict__ logits,
                           int* __restrict__ gcnt,
                           int* __restrict__ srid_p,
                           float* __restrict__ sel_t,
                           int* __restrict__ ntot)
{
    __shared__ int sc[NRULE];
    const int tid = threadIdx.x;
    int h = 0;
#pragma unroll
    for (int b = 0; b < NHIST; ++b) h += ghist_part[b * NRULE + tid];
    const int pd = (h + 15) & ~15;
    sc[tid] = pd;
    for (int off = 1; off < NRULE; off <<= 1) {
        __syncthreads();
        int v = (tid >= off) ? sc[tid - off] : 0;
        __syncthreads();
        sc[tid] += v;
    }
    __syncthreads();
    const int excl = sc[tid] - pd;
    gcnt[tid] = excl;
    for (int q = h; q < pd; ++q) srid_p[excl + q] = tid;
    if (tid == NRULE - 1) *ntot = sc[tid];
    const float invT = 5.65685424949238f;
    const float* __restrict__ lg = logits + (size_t)tid * NBLK;
    float m = -1e30f;
    for (int b = 0; b < NBLK; ++b) m = fmaxf(m, lg[b] * invT);
    float s = 0.0f;
    for (int b = 0; b < NBLK; ++b) s += expf(lg[b] * invT - m);
    const float inv = 1.0f / s;
    for (int b = 0; b < NBLK; ++b)
        sel_t[(size_t)tid * NBLK + b] = expf(lg[b] * invT - m) * inv;
}

// ---------------------------------------------------------------------------
// prep C: scatter tokens to padded slots.
// ---------------------------------------------------------------------------
__global__ void kprep_scatter(const int* __restrict__ rule_ids,
                              int* __restrict__ gcnt,
                              int* __restrict__ perm_p,
                              int* __restrict__ srid_p)
{
    const int i = blockIdx.x * 256 + threadIdx.x;
    const int r = rule_ids[i];
    const int p = atomicAdd(&gcnt[r], 1);
    perm_p[p] = i;
    srid_p[p] = r;
}

// ---------------------------------------------------------------------------
// kmain (fused): 32 slots (2 rule-uniform strips of 16), 512 thr = 8 waves.
// Phase 1: wave (s = w&1, p = w>>1): strip s, K-quarter p; x from global,
//   rings as in R8-k1; t partials -> tred, sel-scaled hidden -> hs_lds.
// Reduce: tred(4 quarters) -> t_bf (bf16, LDS only; no HBM round trip).
// Phase 2: wave (s, col-quarter p): 32 CFs; sob ring 3 ahead; predicated
//   stores (pad rows skipped -> ~19% write-BW saved).
// ---------------------------------------------------------------------------
__global__ __launch_bounds__(512, 4)
void kmain(const float* __restrict__ x,
           const int* __restrict__ perm_p,
           const int* __restrict__ srid_p,
           const unsigned short* __restrict__ ssb,
           const unsigned short* __restrict__ sob,
           const unsigned short* __restrict__ rinf,
           const unsigned short* __restrict__ rof,
           const float* __restrict__ sel_t,
           const int* __restrict__ ntot,
           float* __restrict__ out)
{
    __shared__ __align__(16) float tred[8][16][52];            // 26.6 KB
    __shared__ __align__(16) unsigned short hs_lds[2][16][264];// 16.9 KB
    __shared__ __align__(16) unsigned short t_bf[32][72];      // 4.6 KB

    const int slot0 = blockIdx.x * 32;
    if (slot0 >= *ntot) return;

    const int tid  = threadIdx.x;
    const int lane = tid & 63;
    const int w    = tid >> 6;            // 0..7
    const int s    = w & 1;               // strip
    const int p    = w >> 1;              // K-quarter (ph1) / col-quarter (ph2)
    const int row_l = lane & 15, grp = lane >> 4;
    const int slotbase = slot0 + s * 16;

    const int rid_u = __builtin_amdgcn_readfirstlane(srid_p[slotbase]);
    int tok = perm_p[slotbase + row_l];
    if (tok < 0) tok = 0;

    // =============== phase 1: t = x@shared_in, hidden = x@rule_in ==========
    {
        const float* __restrict__ xr = x + (size_t)tok * INF + p * 512 + (grp << 3);
        const unsigned short* __restrict__ sbase =
            ssb + (size_t)(p * 16) * 1536 + lane * 8;
        const bf16x8 ri0 = *(const bf16x8*)(rinf + ((size_t)rid_u * 2 + 0) * 512 + lane * 8);
        const bf16x8 ri1 = *(const bf16x8*)(rinf + ((size_t)rid_u * 2 + 1) * 512 + lane * 8);

        f32x4 aT0 = {0.f, 0.f, 0.f, 0.f};
        f32x4 aT1 = {0.f, 0.f, 0.f, 0.f};
        f32x4 aT2 = {0.f, 0.f, 0.f, 0.f};
        f32x4 aH  = {0.f, 0.f, 0.f, 0.f};

        float4 xa[4][2];                   // ring, 3 ahead
        bf16x8 wr[3][3];                   // ring, 2 ahead
#pragma unroll
        for (int s_ = 0; s_ < 3; ++s_) {
            xa[s_][0] = *(const float4*)(xr + s_ * 32);
            xa[s_][1] = *(const float4*)(xr + s_ * 32 + 4);
        }
#pragma unroll
        for (int s_ = 0; s_ < 2; ++s_) {
            const unsigned short* sp = sbase + (size_t)s_ * 1536;
            wr[s_][0] = *(const bf16x8*)(sp);
            wr[s_][1] = *(const bf16x8*)(sp + 512);
            wr[s_][2] = *(const bf16x8*)(sp + 1024);
        }
        SBAR();

#pragma unroll
        for (int c = 0; c < 16; ++c) {
            if (c < 13) {                  // x prefetch, 3 ahead
                xa[(c + 3) & 3][0] = *(const float4*)(xr + (c + 3) * 32);
                xa[(c + 3) & 3][1] = *(const float4*)(xr + (c + 3) * 32 + 4);
            }
            if (c < 14) {                  // weights, 2 ahead (L2-hot)
                const unsigned short* sp = sbase + (size_t)(c + 2) * 1536;
                wr[(c + 2) % 3][0] = *(const bf16x8*)(sp);
                wr[(c + 2) % 3][1] = *(const bf16x8*)(sp + 512);
                wr[(c + 2) % 3][2] = *(const bf16x8*)(sp + 1024);
            }
            SBAR();
            const bf16x8 af = cvt8(xa[c & 3][0], xa[c & 3][1]);
            aT0 = MFMA(af, wr[c % 3][0], aT0, 0, 0, 0);
            aT1 = MFMA(af, wr[c % 3][1], aT1, 0, 0, 0);
            aT2 = MFMA(af, wr[c % 3][2], aT2, 0, 0, 0);
            aH  = MFMA(af, (c & 1) ? ri1 : ri0, aH, 0, 0, 0);
            if (c & 1) {
                const int b = p * 8 + (c >> 1);
                const float sel = sel_t[(size_t)rid_u * NBLK + b];
                if (row_l < RANK) {
#pragma unroll
                    for (int q = 0; q < 4; ++q)
                        hs_lds[s][(grp << 2) + q][b * 8 + row_l] =
                            (unsigned short)f2bs(aH[q] * sel);
                }
                aH[0] = 0.f; aH[1] = 0.f; aH[2] = 0.f; aH[3] = 0.f;
            }
            SBAR();
        }

#pragma unroll
        for (int q = 0; q < 4; ++q) {
            const int tk = (grp << 2) + q;
            tred[w][tk][row_l]      = aT0[q];
            tred[w][tk][16 + row_l] = aT1[q];
            tred[w][tk][32 + row_l] = aT2[q];
        }
    }
    __syncthreads();
    {   // reduce 4 K-quarters -> bf16 t (32 slots x 64 cols, K-padded)
        const int sl = tid >> 4;           // 0..31
        const int st = sl >> 4, tk = sl & 15;
        const int c0 = (tid & 15) << 2;    // 0..60
        s16x4 v = {0, 0, 0, 0};
        if (c0 < 48) {
#pragma unroll
            for (int j = 0; j < 4; ++j) {
                const float sm = tred[st][tk][c0 + j] + tred[2 + st][tk][c0 + j]
                               + tred[4 + st][tk][c0 + j] + tred[6 + st][tk][c0 + j];
                v[j] = f2bs(sm);
            }
        }
        *(s16x4*)(&t_bf[sl][c0]) = v;
    }
    __syncthreads();
    SBAR();                                // keep phase-2 setup below the sync

    // =============== phase 2: out = t@shared_out + hs@rule_out =============
    {
        const bf16x8 at0 = *(const bf16x8*)(&t_bf[s * 16 + row_l][grp << 3]);
        const bf16x8 at1 = *(const bf16x8*)(&t_bf[s * 16 + row_l][32 + (grp << 3)]);

        bf16x8 rfv[4];
#pragma unroll
        for (int i = 0; i < 4; ++i)
            rfv[i] = *(const bf16x8*)(rof + ((size_t)rid_u * 4 + i) * 512 + lane * 8);

        const int4 pv = *(const int4*)(perm_p + slotbase + (grp << 2));
        float* const orow0 = out + (size_t)pv.x * OUTF;
        float* const orow1 = out + (size_t)pv.y * OUTF;
        float* const orow2 = out + (size_t)pv.z * OUTF;
        float* const orow3 = out + (size_t)pv.w * OUTF;

        const int CF0 = p * 32;
        const int bb0 = p * 8;
        const unsigned short* __restrict__ sobw = sob + (size_t)CF0 * 1024 + lane * 8;

        bf16x8 sb[4][2];
        bf16x8 ah[2];
        const bf16x8 zz = {0, 0, 0, 0, 0, 0, 0, 0};

#define LOADQ(SL, QI) do { \
        const unsigned short* _sp = sobw + (size_t)(QI) * 1024; \
        sb[SL][0] = *(const bf16x8*)(_sp); \
        sb[SL][1] = *(const bf16x8*)(_sp + 512); \
    } while (0)
#define LOADA(SL, BI) do { \
        ah[SL] = zz; \
        if (lane < 16) \
            ah[SL] = *(const bf16x8*)(&hs_lds[s][lane][(bb0 + (BI)) * 8]); \
    } while (0)

        LOADQ(0, 0); LOADQ(1, 1); LOADQ(2, 2);
        LOADA(0, 0);
        SBAR();

#pragma unroll
        for (int qi = 0; qi < 32; ++qi) {
            if (qi < 29) LOADQ((qi + 3) & 3, qi + 3);
            if ((qi & 3) == 0 && qi < 28) LOADA(((qi >> 2) + 1) & 1, (qi >> 2) + 1);
            SBAR();
            f32x4 acc = {0.f, 0.f, 0.f, 0.f};
            acc = MFMA(at0, sb[qi & 3][0], acc, 0, 0, 0);
            acc = MFMA(at1, sb[qi & 3][1], acc, 0, 0, 0);
            acc = MFMA(ah[(qi >> 2) & 1], rfv[qi & 3], acc, 0, 0, 0);
            const int col = ((CF0 + qi) << 4) + row_l;
            if (pv.x >= 0) orow0[col] = acc[0];
            if (pv.y >= 0) orow1[col] = acc[1];
            if (pv.z >= 0) orow2[col] = acc[2];
            if (pv.w >= 0) orow3[col] = acc[3];
            SBAR();
        }
#undef LOADQ
#undef LOADA
    }
}

extern "C" void kernel_launch(void* const* d_in, const int* in_sizes, int n_in,
                              void* d_out, int out_size, void* d_ws, size_t ws_size,
                              hipStream_t stream)
{
    const float* x          = (const float*)d_in[0];
    const int*   rule_ids   = (const int*)  d_in[1];
    const float* shared_in  = (const float*)d_in[2];
    const float* shared_out = (const float*)d_in[3];
    const float* rule_in    = (const float*)d_in[4];
    const float* rule_out   = (const float*)d_in[5];
    const float* logits     = (const float*)d_in[6];
    float* out = (float*)d_out;

    char* p = (char*)d_ws;
    auto carve = [&p](size_t bytes) {
        char* r = p;
        p += (bytes + 255) & ~(size_t)255;
        return r;
    };
    int*            perm_p = (int*)carve(MAXSLOT * 4);
    int*            srid_p = (int*)carve(MAXSLOT * 4);
    unsigned short* ssb    = (unsigned short*)carve(64 * 3 * 512 * 2);
    unsigned short* sob    = (unsigned short*)carve(128 * 2 * 512 * 2);
    unsigned short* rinf   = (unsigned short*)carve((size_t)NRULE * 2 * 512 * 2);
    unsigned short* rof    = (unsigned short*)carve((size_t)NRULE * 4 * 512 * 2);
    float*          sel_t  = (float*)carve((size_t)NRULE * NBLK * 4);
    int*            ghistp = (int*)carve((size_t)NHIST * NRULE * 4);
    int*            gcnt   = (int*)carve(NRULE * 4);
    int*            ntot   = (int*)carve(4);

    kprep_a<<<dim3(160), dim3(256), 0, stream>>>(
        rule_ids, shared_in, shared_out, rule_in, rule_out,
        ssb, sob, rinf, rof, ghistp, perm_p, srid_p);
    kprep_scan<<<dim3(1), dim3(256), 0, stream>>>(
        ghistp, logits, gcnt, srid_p, sel_t, ntot);
    kprep_scatter<<<dim3(64), dim3(256), 0, stream>>>(
        rule_ids, gcnt, perm_p, srid_p);
    kmain<<<dim3(NTILE32), dim3(512), 0, stream>>>(
        x, perm_p, srid_p, ssb, sob, rinf, rof, sel_t, ntot, out);
}

// Round 10
// 94.298 us; speedup vs baseline: 1.2503x; 1.2503x over previous
//
#include <hip/hip_runtime.h>
#include <hip/hip_bf16.h>
#include <math.h>

#define NTOK  16384
#define INF   2048
#define OUTF  2048
#define SR    45
#define RANK  8
#define BLK   64
#define NBLK  32
#define NRULE 256
#define NHIST 32
#define MAXSLOT (NTOK + NRULE * 15)   // 20224
#define NTILE32 (MAXSLOT / 32)        // 632 tiles of 32 slots

typedef __attribute__((ext_vector_type(8))) short bf16x8;
typedef __attribute__((ext_vector_type(4))) float f32x4;
typedef __attribute__((ext_vector_type(4))) short s16x4;

typedef const __attribute__((address_space(1))) unsigned int GU32;
typedef __attribute__((address_space(3))) unsigned int LU32;

#define MFMA __builtin_amdgcn_mfma_f32_16x16x32_bf16
#define SBAR() __builtin_amdgcn_sched_barrier(0)

__device__ inline short f2bs(float f) {
    __hip_bfloat16 h = __float2bfloat16(f);
    return *reinterpret_cast<short*>(&h);
}
__device__ inline bf16x8 cvt8(const float4& a, const float4& b) {
    bf16x8 r;
    r[0] = f2bs(a.x); r[1] = f2bs(a.y); r[2] = f2bs(a.z); r[3] = f2bs(a.w);
    r[4] = f2bs(b.x); r[5] = f2bs(b.y); r[6] = f2bs(b.z); r[7] = f2bs(b.w);
    return r;
}

// ---------------------------------------------------------------------------
// prep A: blocks 0..127 pack weights into MFMA B-frag layout (bf16);
//         blocks 128..159 per-block histogram slabs + init perm/srid.
// ---------------------------------------------------------------------------
__global__ void kprep_a(const int* __restrict__ rule_ids,
                        const float* __restrict__ shared_in,
                        const float* __restrict__ shared_out,
                        const float* __restrict__ rule_in,
                        const float* __restrict__ rule_out,
                        unsigned short* __restrict__ ssb,   // [64ch][3nf][64][8]
                        unsigned short* __restrict__ sob,   // [128CF][2kc][64][8]
                        unsigned short* __restrict__ rinf,  // [256][2half][64][8]
                        unsigned short* __restrict__ rof,   // [256][4cf][64][8]
                        int* __restrict__ ghist_part,       // [32][256]
                        int* __restrict__ perm_p,
                        int* __restrict__ srid_p)
{
    if (blockIdx.x < 128) {
        const int tid = blockIdx.x * 256 + threadIdx.x;
        const int stride = 128 * 256;
        for (int idx = tid; idx < 64 * 3 * 512; idx += stride) {
            int ch = idx / 1536, rem = idx - ch * 1536;
            int nf = rem / 512;
            int l = (rem >> 3) & 63, j = idx & 7;
            int k = ch * 32 + ((l >> 4) << 3) + j;
            int col = nf * 16 + (l & 15);
            ssb[idx] = (col < SR) ? (unsigned short)f2bs(shared_in[(size_t)k * SR + col]) : 0;
        }
        for (int idx = tid; idx < 128 * 2 * 512; idx += stride) {
            int CF = idx >> 10;
            int kc = (idx >> 9) & 1;
            int l = (idx >> 3) & 63, j = idx & 7;
            int k = kc * 32 + ((l >> 4) << 3) + j;
            int col = CF * 16 + (l & 15);
            sob[idx] = (k < SR) ? (unsigned short)f2bs(shared_out[(size_t)k * OUTF + col]) : 0;
        }
        for (int idx = tid; idx < NRULE * 2 * 512; idx += stride) {
            int rid = idx >> 10;
            int half = (idx >> 9) & 1;
            int l = (idx >> 3) & 63, j = idx & 7;
            int r = l & 15;
            int s = half * 32 + ((l >> 4) << 3) + j;
            rinf[idx] = (r < RANK) ? (unsigned short)f2bs(rule_in[(size_t)rid * 512 + s * RANK + r]) : 0;
        }
        for (int idx = tid; idx < NRULE * 4 * 512; idx += stride) {
            int rid = idx >> 11;
            int cf = (idx >> 9) & 3;
            int l = (idx >> 3) & 63, j = idx & 7;
            int k = ((l >> 4) << 3) + j;
            int c = cf * 16 + (l & 15);
            rof[idx] = (k < RANK) ? (unsigned short)f2bs(rule_out[(size_t)rid * 512 + k * BLK + c]) : 0;
        }
    } else {
        __shared__ int lh[NRULE];
        const int tid = threadIdx.x;
        const int hb = blockIdx.x - 128;          // 0..31
        lh[tid] = 0;
        __syncthreads();
        const int base = hb * 512;
        atomicAdd(&lh[rule_ids[base + tid]], 1);
        atomicAdd(&lh[rule_ids[base + 256 + tid]], 1);
        __syncthreads();
        ghist_part[hb * NRULE + tid] = lh[tid];
        for (int j = tid; j < MAXSLOT / 32; j += 256) {
            int idx = hb * (MAXSLOT / 32) + j;
            perm_p[idx] = -1;
            srid_p[idx] = 0;
        }
    }
}

// ---------------------------------------------------------------------------
// prep B (1 block, 256 thr): sum hist slabs, scan, pad srid, sel, ntot
// ---------------------------------------------------------------------------
__global__ void kprep_scan(const int* __restrict__ ghist_part,
                           const float* __restrict__ logits,
                           int* __restrict__ gcnt,
                           int* __restrict__ srid_p,
                           float* __restrict__ sel_t,
                           int* __restrict__ ntot)
{
    __shared__ int sc[NRULE];
    const int tid = threadIdx.x;
    int h = 0;
#pragma unroll
    for (int b = 0; b < NHIST; ++b) h += ghist_part[b * NRULE + tid];
    const int pd = (h + 15) & ~15;
    sc[tid] = pd;
    for (int off = 1; off < NRULE; off <<= 1) {
        __syncthreads();
        int v = (tid >= off) ? sc[tid - off] : 0;
        __syncthreads();
        sc[tid] += v;
    }
    __syncthreads();
    const int excl = sc[tid] - pd;
    gcnt[tid] = excl;
    for (int q = h; q < pd; ++q) srid_p[excl + q] = tid;
    if (tid == NRULE - 1) *ntot = sc[tid];
    const float invT = 5.65685424949238f;
    const float* __restrict__ lg = logits + (size_t)tid * NBLK;
    float m = -1e30f;
    for (int b = 0; b < NBLK; ++b) m = fmaxf(m, lg[b] * invT);
    float s = 0.0f;
    for (int b = 0; b < NBLK; ++b) s += expf(lg[b] * invT - m);
    const float inv = 1.0f / s;
    for (int b = 0; b < NBLK; ++b)
        sel_t[(size_t)tid * NBLK + b] = expf(lg[b] * invT - m) * inv;
}

// ---------------------------------------------------------------------------
// prep C: scatter tokens to padded slots.
// ---------------------------------------------------------------------------
__global__ void kprep_scatter(const int* __restrict__ rule_ids,
                              int* __restrict__ gcnt,
                              int* __restrict__ perm_p,
                              int* __restrict__ srid_p)
{
    const int i = blockIdx.x * 256 + threadIdx.x;
    const int r = rule_ids[i];
    const int p = atomicAdd(&gcnt[r], 1);
    perm_p[p] = i;
    srid_p[p] = r;
}

// ---------------------------------------------------------------------------
// kmain: 32 slots (2 rule-uniform strips), 256 thr = 4 waves = (strip s, kh).
// Phase 1 (m97-style): x staged to LDS via global_load_lds DMA (cannot be
//   sunk by the compiler), double-buffered 64-col chunks, ONE __syncthreads
//   per chunk; XOR source-swizzle kills ds_read bank conflicts (T21).
//   Wave (s,kh) computes sub kh (32 k) of each chunk; hidden partials summed
//   per-chunk via a small LDS buffer; t reduced at the end (tred overlays the
//   dead x-buffer; t_bf overlays hstmp).
// Phase 2: wave (s, p) covers cols [p*1024, +1024); sob ring; predicated
//   stores (pad rows skipped).
// LDS total 37.9 KB -> 4 blocks/CU.
// ---------------------------------------------------------------------------
__global__ __launch_bounds__(256, 4)
void kmain(const float* __restrict__ x,
           const int* __restrict__ perm_p,
           const int* __restrict__ srid_p,
           const unsigned short* __restrict__ ssb,
           const unsigned short* __restrict__ sob,
           const unsigned short* __restrict__ rinf,
           const unsigned short* __restrict__ rof,
           const float* __restrict__ sel_t,
           const int* __restrict__ ntot,
           float* __restrict__ out)
{
    __shared__ __align__(16) float xbuf[2][2048];               // 16 KB
    __shared__ __align__(16) unsigned short hs_lds[2][16][264]; // 16.9 KB
    __shared__ __align__(16) char pool[4608];                   // hstmp / t_bf

#define HST(PB, S, KH, SL, R) \
    (((float*)pool)[(((((PB) * 2 + (S)) * 2 + (KH)) * 16 + (SL)) * 8) + (R)])
#define TBF(SL, C) (((unsigned short*)pool)[(SL) * 72 + (C)])
#define TRD(W, SL, C) (((float*)xbuf)[(((W) * 16 + (SL)) * 52) + (C)])

    const int slot0 = blockIdx.x * 32;
    if (slot0 >= *ntot) return;

    const int tid  = threadIdx.x;
    const int lane = tid & 63;
    const int w    = tid >> 6;            // 0..3
    const int s    = w & 1;               // strip
    const int kh   = w >> 1;              // k-sub (ph1) / col-half (ph2)
    const int row_l = lane & 15, grp = lane >> 4;
    const int slotbase = slot0 + s * 16;

    const int rid_u = __builtin_amdgcn_readfirstlane(srid_p[slotbase]);

    // ---- staging sources: thread covers rows r0 and r0+16, unit u ---------
    const int r0 = tid >> 4;
    const int u  = tid & 15;
    int tokA = perm_p[slot0 + r0];       if (tokA < 0) tokA = 0;
    int tokB = perm_p[slot0 + r0 + 16];  if (tokB < 0) tokB = 0;
    const char* gA = (const char*)(x + (size_t)tokA * INF) + ((u ^ (r0 & 7)) << 4);
    const char* gB = (const char*)(x + (size_t)tokB * INF) + ((u ^ (r0 & 7)) << 4);

#define STAGE(CH) do { \
        char* _lb = (char*)xbuf + (((CH) & 1) << 13) + (w << 10); \
        const size_t _o = (size_t)(CH) << 8; \
        __builtin_amdgcn_global_load_lds((GU32*)(gA + _o), (LU32*)_lb,          16, 0, 0); \
        __builtin_amdgcn_global_load_lds((GU32*)(gB + _o), (LU32*)(_lb + 4096), 16, 0, 0); \
    } while (0)

    // ---- ds_read byte offsets for this wave's fragment --------------------
    const int rphys = s * 16 + row_l;
    const int offA = (rphys * 16 + ((kh * 8 + grp * 2 + 0) ^ (row_l & 7))) << 4;
    const int offB = (rphys * 16 + ((kh * 8 + grp * 2 + 1) ^ (row_l & 7))) << 4;

    const bf16x8 ri = *(const bf16x8*)(rinf + ((size_t)rid_u * 2 + kh) * 512 + lane * 8);

    f32x4 aT0 = {0.f, 0.f, 0.f, 0.f};
    f32x4 aT1 = {0.f, 0.f, 0.f, 0.f};
    f32x4 aT2 = {0.f, 0.f, 0.f, 0.f};

    STAGE(0);
    __syncthreads();

    for (int ch = 0; ch < 32; ++ch) {
        if (ch < 31) STAGE(ch + 1);       // DMA in flight across this compute

        // finish hidden of previous chunk (hstmp written before last barrier)
        if (ch > 0) {
            const int b = ch - 1, pb = b & 1;
            const int sl = kh * 8 + (lane >> 3), r = lane & 7;
            const float v = HST(pb, s, 0, sl, r) + HST(pb, s, 1, sl, r);
            hs_lds[s][sl][b * 8 + r] =
                (unsigned short)f2bs(v * sel_t[(size_t)rid_u * NBLK + b]);
        }

        // compute sub kh of chunk ch
        {
            const char* xb = (const char*)xbuf + ((ch & 1) << 13);
            const float4 fa = *(const float4*)(xb + offA);
            const float4 fb = *(const float4*)(xb + offB);
            const bf16x8 af = cvt8(fa, fb);
            const unsigned short* sp = ssb + (size_t)(ch * 2 + kh) * 1536 + lane * 8;
            f32x4 aH = {0.f, 0.f, 0.f, 0.f};
            aT0 = MFMA(af, *(const bf16x8*)(sp),        aT0, 0, 0, 0);
            aT1 = MFMA(af, *(const bf16x8*)(sp + 512),  aT1, 0, 0, 0);
            aT2 = MFMA(af, *(const bf16x8*)(sp + 1024), aT2, 0, 0, 0);
            aH  = MFMA(af, ri, aH, 0, 0, 0);
            if (row_l < RANK) {
#pragma unroll
                for (int q = 0; q < 4; ++q)
                    HST(ch & 1, s, kh, (grp << 2) + q, row_l) = aH[q];
            }
        }
        __syncthreads();                  // DMA(ch+1) landed; hstmp[ch] visible
    }

    // ---- epilogue: hidden for chunk 31, t partials -> tred (xbuf reuse) ---
    {
        const int b = 31, pb = 1;
        const int sl = kh * 8 + (lane >> 3), r = lane & 7;
        const float v = HST(pb, s, 0, sl, r) + HST(pb, s, 1, sl, r);
        hs_lds[s][sl][b * 8 + r] =
            (unsigned short)f2bs(v * sel_t[(size_t)rid_u * NBLK + b]);
    }
#pragma unroll
    for (int q = 0; q < 4; ++q) {
        const int sl = (grp << 2) + q;
        TRD(w, sl, row_l)      = aT0[q];
        TRD(w, sl, 16 + row_l) = aT1[q];
        TRD(w, sl, 32 + row_l) = aT2[q];
    }
    __syncthreads();
    {   // reduce kh pairs -> bf16 t (32 slots x 64 cols, K-padded)
        const int sl = tid >> 3;           // 0..31
        const int st = sl >> 4, tk = sl & 15;
        const int cidx = tid & 7;
        if (cidx < 6) {
            const int c0 = cidx << 3;
            s16x4 v0, v1;
#pragma unroll
            for (int j = 0; j < 4; ++j) {
                v0[j] = f2bs(TRD(st, tk, c0 + j)     + TRD(st + 2, tk, c0 + j));
                v1[j] = f2bs(TRD(st, tk, c0 + 4 + j) + TRD(st + 2, tk, c0 + 4 + j));
            }
            *(s16x4*)(&TBF(sl, c0))     = v0;
            *(s16x4*)(&TBF(sl, c0 + 4)) = v1;
        } else {
            const int c0 = 48 + ((cidx - 6) << 3);
            const s16x4 z = {0, 0, 0, 0};
            *(s16x4*)(&TBF(sl, c0))     = z;
            *(s16x4*)(&TBF(sl, c0 + 4)) = z;
        }
    }
    __syncthreads();

    // ================= phase 2: out = t@shared_out + hs@rule_out ===========
    {
        const int p = kh;                  // col-half: [p*1024, +1024)
        const bf16x8 at0 = *(const bf16x8*)(&TBF(s * 16 + row_l, grp << 3));
        const bf16x8 at1 = *(const bf16x8*)(&TBF(s * 16 + row_l, 32 + (grp << 3)));

        bf16x8 rfv[4];
#pragma unroll
        for (int i = 0; i < 4; ++i)
            rfv[i] = *(const bf16x8*)(rof + ((size_t)rid_u * 4 + i) * 512 + lane * 8);

        const int4 pv = *(const int4*)(perm_p + slotbase + (grp << 2));
        float* const orow0 = out + (size_t)pv.x * OUTF;
        float* const orow1 = out + (size_t)pv.y * OUTF;
        float* const orow2 = out + (size_t)pv.z * OUTF;
        float* const orow3 = out + (size_t)pv.w * OUTF;

        const int CF0 = p * 64;
        const int bb0 = p * 16;
        const unsigned short* __restrict__ sobw = sob + (size_t)CF0 * 1024 + lane * 8;

        bf16x8 sb[4][2];
        bf16x8 ah[2];
        const bf16x8 zz = {0, 0, 0, 0, 0, 0, 0, 0};

#define LOADQ(SL, QI) do { \
        const unsigned short* _sp = sobw + (size_t)(QI) * 1024; \
        sb[SL][0] = *(const bf16x8*)(_sp); \
        sb[SL][1] = *(const bf16x8*)(_sp + 512); \
    } while (0)
#define LOADA(SL, BI) do { \
        ah[SL] = zz; \
        if (lane < 16) \
            ah[SL] = *(const bf16x8*)(&hs_lds[s][lane][(bb0 + (BI)) * 8]); \
    } while (0)

        LOADQ(0, 0); LOADQ(1, 1); LOADQ(2, 2);
        LOADA(0, 0);
        SBAR();

#pragma unroll
        for (int qi = 0; qi < 64; ++qi) {
            if (qi < 61) LOADQ((qi + 3) & 3, qi + 3);
            if ((qi & 3) == 0 && qi < 60) LOADA(((qi >> 2) + 1) & 1, (qi >> 2) + 1);
            SBAR();
            f32x4 acc = {0.f, 0.f, 0.f, 0.f};
            acc = MFMA(at0, sb[qi & 3][0], acc, 0, 0, 0);
            acc = MFMA(at1, sb[qi & 3][1], acc, 0, 0, 0);
            acc = MFMA(ah[(qi >> 2) & 1], rfv[qi & 3], acc, 0, 0, 0);
            const int col = ((CF0 + qi) << 4) + row_l;
            if (pv.x >= 0) orow0[col] = acc[0];
            if (pv.y >= 0) orow1[col] = acc[1];
            if (pv.z >= 0) orow2[col] = acc[2];
            if (pv.w >= 0) orow3[col] = acc[3];
            SBAR();
        }
#undef LOADQ
#undef LOADA
    }
}

extern "C" void kernel_launch(void* const* d_in, const int* in_sizes, int n_in,
                              void* d_out, int out_size, void* d_ws, size_t ws_size,
                              hipStream_t stream)
{
    const float* x          = (const float*)d_in[0];
    const int*   rule_ids   = (const int*)  d_in[1];
    const float* shared_in  = (const float*)d_in[2];
    const float* shared_out = (const float*)d_in[3];
    const float* rule_in    = (const float*)d_in[4];
    const float* rule_out   = (const float*)d_in[5];
    const float* logits     = (const float*)d_in[6];
    float* out = (float*)d_out;

    char* p = (char*)d_ws;
    auto carve = [&p](size_t bytes) {
        char* r = p;
        p += (bytes + 255) & ~(size_t)255;
        return r;
    };
    int*            perm_p = (int*)carve(MAXSLOT * 4);
    int*            srid_p = (int*)carve(MAXSLOT * 4);
    unsigned short* ssb    = (unsigned short*)carve(64 * 3 * 512 * 2);
    unsigned short* sob    = (unsigned short*)carve(128 * 2 * 512 * 2);
    unsigned short* rinf   = (unsigned short*)carve((size_t)NRULE * 2 * 512 * 2);
    unsigned short* rof    = (unsigned short*)carve((size_t)NRULE * 4 * 512 * 2);
    float*          sel_t  = (float*)carve((size_t)NRULE * NBLK * 4);
    int*            ghistp = (int*)carve((size_t)NHIST * NRULE * 4);
    int*            gcnt   = (int*)carve(NRULE * 4);
    int*            ntot   = (int*)carve(4);

    kprep_a<<<dim3(160), dim3(256), 0, stream>>>(
        rule_ids, shared_in, shared_out, rule_in, rule_out,
        ssb, sob, rinf, rof, ghistp, perm_p, srid_p);
    kprep_scan<<<dim3(1), dim3(256), 0, stream>>>(
        ghistp, logits, gcnt, srid_p, sel_t, ntot);
    kprep_scatter<<<dim3(64), dim3(256), 0, stream>>>(
        rule_ids, gcnt, perm_p, srid_p);
    kmain<<<dim3(NTILE32), dim3(256), 0, stream>>>(
        x, perm_p, srid_p, ssb, sob, rinf, rof, sel_t, ntot, out);
}